// Round 6
// baseline (74.272 us; speedup 1.0000x reference)
//
#include <hip/hip_runtime.h>
#include <hip/hip_bf16.h>
#include <math.h>

// GConvLSTM cell via MFMA (graph inputs are dead code in the reference).
// Gate GEMM: g[node][0:64] = [x(8) | h(16) | pad8] @ W(32x64) + (bx+bh+b_gates),
// one wave = 16 nodes/iter, 4x mfma_f32_16x16x32_bf16 (one per gate).
// D-layout (verified R3): lane holds (d = lane&15, nodes rb..rb+3, rb = gb + (lane>>4)*4).
// R6 vs R5: revert reduce to __shfl_xor width-16 (R5's DPP row_ror reduce was
// WRONG on hardware -> out absmax 1.35; shfl is the R4-proven path). Keep:
//  - IW 8 -> 4: 15625 waves (~15/SIMD) for 2x latency-hiding oversubscription
//  - float4 out store per 16-lane group
//  - loop kept rolled to hold VGPR (~60) at 8 waves/SIMD residency
// d_out layout: [N] out | [N*16] h_new | [N*16] c_new.  Requires n % 16 == 0.

typedef short bf16x8 __attribute__((ext_vector_type(8)));
typedef float f32x4 __attribute__((ext_vector_type(4)));

#define LOG2E 1.44269504088896f

__device__ __forceinline__ float sig1(float v) {
    return __builtin_amdgcn_rcpf(1.0f + __builtin_amdgcn_exp2f(-LOG2E * v));
}
__device__ __forceinline__ float tanh1(float v) {
    return 1.0f - 2.0f * __builtin_amdgcn_rcpf(__builtin_amdgcn_exp2f((2.0f * LOG2E) * v) + 1.0f);
}
__device__ __forceinline__ f32x4 sig4(f32x4 v) {
    f32x4 r; r[0]=sig1(v[0]); r[1]=sig1(v[1]); r[2]=sig1(v[2]); r[3]=sig1(v[3]); return r;
}
__device__ __forceinline__ f32x4 tanh4(f32x4 v) {
    f32x4 r; r[0]=tanh1(v[0]); r[1]=tanh1(v[1]); r[2]=tanh1(v[2]); r[3]=tanh1(v[3]); return r;
}
__device__ __forceinline__ short f2bf(float f) {
    __bf16 b = (__bf16)f;          // pairs fuse to v_cvt_pk_bf16_f32
    short s; __builtin_memcpy(&s, &b, 2); return s;
}
__device__ __forceinline__ f32x4 max4z(f32x4 a) {
    f32x4 r; r[0]=fmaxf(a[0],0.f); r[1]=fmaxf(a[1],0.f); r[2]=fmaxf(a[2],0.f); r[3]=fmaxf(a[3],0.f); return r;
}

#define IW 4                       // 64-node tiles per block
#define NPB (64 * IW)              // 256 nodes per block

__global__ __launch_bounds__(256) void lstm_mfma_kernel(
    const float* __restrict__ x,       // N x 8
    const float* __restrict__ h,       // N x 16
    const float* __restrict__ c,       // N x 16
    const float* __restrict__ Wx,      // 8 x 64
    const float* __restrict__ bx,      // 64
    const float* __restrict__ Wh,      // 16 x 64
    const float* __restrict__ bh,      // 64
    const float* __restrict__ w_peep,  // 3 x 16
    const float* __restrict__ b_gates, // 4 x 16
    const float* __restrict__ W_lin,   // 16
    const float* __restrict__ b_lin,   // 1
    float* __restrict__ dout,
    int n)
{
    const int lane = threadIdx.x & 63;
    const int wave = threadIdx.x >> 6;
    const int d  = lane & 15;   // output dim within gate / A row offset
    const int kb = lane >> 4;   // k-block (8 k's each)

    // ---- B fragments: bfrag[t][e] = W[kb*8+e][t*16+d], W = [Wx; Wh; 0pad]
    // Rows 24..31 MUST be exactly 0 (kb==3 A-frag is garbage and relies on it).
    bf16x8 bfrag[4];
    #pragma unroll
    for (int t = 0; t < 4; ++t) {
        #pragma unroll
        for (int e = 0; e < 8; ++e) {
            const int r = kb * 8 + e;
            float w = 0.0f;
            if (r < 8)        w = Wx[r * 64 + t * 16 + d];
            else if (r < 24)  w = Wh[(r - 8) * 64 + t * 16 + d];
            bfrag[t][e] = f2bf(w);
        }
    }

    // ---- per-lane epilogue constants (b_gates folded into MFMA bias)
    const float biasI = bx[d]      + bh[d]      + b_gates[d];
    const float biasF = bx[16 + d] + bh[16 + d] + b_gates[16 + d];
    const float biasC = bx[32 + d] + bh[32 + d] + b_gates[32 + d];
    const float biasO = bx[48 + d] + bh[48 + d] + b_gates[48 + d];
    const float p0 = w_peep[d], p1 = w_peep[16 + d], p2 = w_peep[32 + d];
    const float wl = W_lin[d];
    const float bl = b_lin[0];

    const unsigned blockBase = (unsigned)blockIdx.x * NPB;
    const unsigned gb0   = blockBase + (unsigned)wave * 16u;  // wave's first node
    const unsigned node0 = gb0 + (unsigned)d;

    // per-lane A pointer: x rows for kb==0, h rows otherwise (kb==3 garbage-ok)
    const float* aptr;
    unsigned astride;
    if (kb == 0) { aptr = x + (size_t)node0 * 8;                        astride = 64u * 8;  }
    else         { aptr = h + (size_t)node0 * 16 + ((kb == 2) ? 8 : 0); astride = 64u * 16; }

    unsigned co = (gb0 + (unsigned)kb * 4u) * 16u + (unsigned)d; // c/h_new/c_new offset
    unsigned ro =  gb0 + (unsigned)kb * 4u;                      // out offset
    float* hob = dout + (size_t)n;        // h_new base
    float* cob = dout + (size_t)n * 17;   // c_new base

#define BODY                                                                   \
    {                                                                          \
        float4 a0 = *reinterpret_cast<const float4*>(aptr);                    \
        float4 a1 = *reinterpret_cast<const float4*>(aptr + 4);                \
        bf16x8 af;                                                             \
        af[0] = f2bf(a0.x); af[1] = f2bf(a0.y);                                \
        af[2] = f2bf(a0.z); af[3] = f2bf(a0.w);                                \
        af[4] = f2bf(a1.x); af[5] = f2bf(a1.y);                                \
        af[6] = f2bf(a1.z); af[7] = f2bf(a1.w);                                \
        f32x4 accI = {biasI, biasI, biasI, biasI};                             \
        f32x4 accF = {biasF, biasF, biasF, biasF};                             \
        f32x4 accC = {biasC, biasC, biasC, biasC};                             \
        f32x4 accO = {biasO, biasO, biasO, biasO};                             \
        accI = __builtin_amdgcn_mfma_f32_16x16x32_bf16(af, bfrag[0], accI, 0, 0, 0); \
        accF = __builtin_amdgcn_mfma_f32_16x16x32_bf16(af, bfrag[1], accF, 0, 0, 0); \
        accC = __builtin_amdgcn_mfma_f32_16x16x32_bf16(af, bfrag[2], accC, 0, 0, 0); \
        accO = __builtin_amdgcn_mfma_f32_16x16x32_bf16(af, bfrag[3], accO, 0, 0, 0); \
        f32x4 cv; cv[0] = c[co]; cv[1] = c[co + 16];                           \
        cv[2] = c[co + 32]; cv[3] = c[co + 48];                                \
        f32x4 iv = sig4(p0 * cv + accI);                                       \
        f32x4 fv = sig4(p1 * cv + accF);                                       \
        f32x4 tv = tanh4(accC);                                                \
        f32x4 cn = fv * cv + iv * tv;                                          \
        f32x4 ov = sig4(p2 * cn + accO);                                       \
        f32x4 hn = ov * tanh4(cn);                                             \
        hob[co] = hn[0]; hob[co + 16] = hn[1];                                 \
        hob[co + 32] = hn[2]; hob[co + 48] = hn[3];                            \
        cob[co] = cn[0]; cob[co + 16] = cn[1];                                 \
        cob[co + 32] = cn[2]; cob[co + 48] = cn[3];                            \
        f32x4 os = max4z(hn) * wl;                                             \
        _Pragma("unroll")                                                      \
        for (int m = 1; m < 16; m <<= 1) {                                     \
            os[0] += __shfl_xor(os[0], m, 16);                                 \
            os[1] += __shfl_xor(os[1], m, 16);                                 \
            os[2] += __shfl_xor(os[2], m, 16);                                 \
            os[3] += __shfl_xor(os[3], m, 16);                                 \
        }                                                                      \
        if (d == 0) {                                                          \
            float4 o4 = make_float4(os[0] + bl, os[1] + bl,                    \
                                    os[2] + bl, os[3] + bl);                   \
            *reinterpret_cast<float4*>(dout + ro) = o4;                        \
        }                                                                      \
        aptr += astride; co += 1024u; ro += 64u;                               \
    }

    if (blockBase + NPB <= (unsigned)n) {
        // full block: exact trip count, no bounds checks; keep rolled for VGPR
        #pragma unroll 1
        for (int it = 0; it < IW; ++it) BODY
    } else {
        // tail block (at most one): group-granular bounds check (n % 16 == 0)
        #pragma unroll 1
        for (int it = 0; it < IW; ++it) {
            if (gb0 + (unsigned)(it * 64) >= (unsigned)n) break;
            BODY
        }
    }
#undef BODY
}

extern "C" void kernel_launch(void* const* d_in, const int* in_sizes, int n_in,
                              void* d_out, int out_size, void* d_ws, size_t ws_size,
                              hipStream_t stream) {
    const float* x       = (const float*)d_in[0];
    // d_in[1] = edge_index (int64, unused), d_in[2] = edge_attr (unused)
    const float* h       = (const float*)d_in[3];
    const float* c       = (const float*)d_in[4];
    const float* Wx      = (const float*)d_in[5];
    const float* bx      = (const float*)d_in[6];
    const float* Wh      = (const float*)d_in[7];
    const float* bh      = (const float*)d_in[8];
    const float* w_peep  = (const float*)d_in[9];
    const float* b_gates = (const float*)d_in[10];
    const float* W_lin   = (const float*)d_in[11];
    const float* b_lin   = (const float*)d_in[12];
    float* out = (float*)d_out;

    const int n = in_sizes[0] / 8;  // N = 1,000,000
    const int blocks = (n + NPB - 1) / NPB;
    lstm_mfma_kernel<<<blocks, 256, 0, stream>>>(
        x, h, c, Wx, bx, Wh, bh, w_peep, b_gates, W_lin, b_lin, out, n);
}